// Round 4
// baseline (347.927 us; speedup 1.0000x reference)
//
#include <hip/hip_runtime.h>
#include <hip/hip_bf16.h>

// Capsule dynamic routing, round 4: fused logits+softmax, de-duplicated reads.
// x[64][2048][16] f32, W[32][2048][16][16] f32 -> v[64][32][16] f32.
//
// Identity: b_k = (sum_{i<k} v_i) . u_hat -> carry only vsum[64][32][16].
// Pass 0: c uniform (1/32) -> wsum+reduce. Passes 1,2: LS (fused
// logits+softmax -> C), wsum (b-tile loop INSIDE: Wbf read once), reduce.
//
// LS: wave = (j, b-tile). Per n: A=Wbf[n][j] frag, B=xbf[b][j] (K=16, upper
// half zeroed), MFMA -> u; logit partial = vsum.u, folded over g via
// shfl_xor(16,32) -> every lane holds logit[n] for its b. In-lane softmax over
// the 32 regs (no exchange). g==0 lanes store C[j][n][b] (64B/row). Block's 4
// waves share j -> Wbf rows L1-hot; xbf read exactly once kernel-wide.
//
// wsum: wave = (chunk, n); K=32 packs 2 j per MFMA; af read once, then 4
// b-tiles accumulate into 4 f32x4 accs. x kept f32 for numerics (c*x rounded
// once). sp[chunk][n][b][d] partials; reduce folds 32 chunks + squash.
//
// MFMA layouts (m89/m91/m120-verified): C/D col=lane&15, row=(lane>>4)*4+reg;
// A[m=lane&15][k=(lane>>4)*8+t].

#define J_DIM 2048

typedef __attribute__((ext_vector_type(8))) short bf16x8;
typedef __attribute__((ext_vector_type(4))) float f32x4;

__device__ inline short f2bf(float f) {
    union { float f; unsigned u; } v; v.f = f;
    unsigned r = v.u + 0x7FFFu + ((v.u >> 16) & 1u);   // RNE
    return (short)(r >> 16);
}

__global__ __launch_bounds__(256)
void cvt_bf16(const float* __restrict__ src, short* __restrict__ dst, int n8) {
    int id = blockIdx.x * 256 + threadIdx.x;
    if (id >= n8) return;
    const float4* s = (const float4*)(src + (size_t)id * 8);
    float4 a = s[0], b = s[1];
    short t[8] = { f2bf(a.x), f2bf(a.y), f2bf(a.z), f2bf(a.w),
                   f2bf(b.x), f2bf(b.y), f2bf(b.z), f2bf(b.w) };
    *(bf16x8*)(dst + (size_t)id * 8) = *(bf16x8*)t;
}

// C[j][n][b] = softmax_n( vsum[b,n,:] . u_hat[b,n,j,:] )
// grid(2048) x 256 thr; wave w = b-tile, block = one j.
__global__ __launch_bounds__(256)
void logits_softmax_k(const short* __restrict__ Wbf, const short* __restrict__ xbf,
                      const float* __restrict__ vsum, float* __restrict__ C) {
    const int t = threadIdx.x, lane = t & 63, bt = t >> 6;
    const int col = lane & 15, g = lane >> 4;
    const int j = blockIdx.x;
    const int b = bt * 16 + col;

    bf16x8 xb = (bf16x8){0, 0, 0, 0, 0, 0, 0, 0};
    if (lane < 32)
        xb = *(const bf16x8*)(xbf + ((size_t)b * J_DIM + j) * 16 + (g & 1) * 8);

    float logit[32];
#pragma unroll
    for (int n = 0; n < 32; ++n) {
        // A[m=col=d][k=g*8+t]; k>=16 garbage, nulled by xb=0 on lanes 32..63
        bf16x8 af = *(const bf16x8*)(Wbf + ((size_t)n * J_DIM + j) * 256 + col * 16 + g * 8);
        f32x4 u = __builtin_amdgcn_mfma_f32_16x16x32_bf16(
            af, xb, (f32x4){0.f, 0.f, 0.f, 0.f}, 0, 0, 0);
        float4 vv = *(const float4*)(vsum + ((size_t)b * 32 + n) * 16 + g * 4);
        float lp = vv.x * u[0] + vv.y * u[1] + vv.z * u[2] + vv.w * u[3];
        lp += __shfl_xor(lp, 16);
        lp += __shfl_xor(lp, 32);          // all lanes: logit(b, n)
        logit[n] = lp;
    }

    float mx = logit[0];
#pragma unroll
    for (int n = 1; n < 32; ++n) mx = fmaxf(mx, logit[n]);
    float Z = 0.f;
#pragma unroll
    for (int n = 0; n < 32; ++n) { logit[n] = __expf(logit[n] - mx); Z += logit[n]; }
    float rz = __builtin_amdgcn_rcpf(Z);

    if (g == 0) {
        float* row = C + (size_t)j * 32 * 64 + b;
#pragma unroll
        for (int n = 0; n < 32; ++n) row[n * 64] = logit[n] * rz;
    }
}

// sp[chunk][n][b][d] = sum_{j in chunk} c[b,n,j] * u_hat[b,n,j,d]
// grid(32 chunks, 8 ngroups) x 256 thr; wave = one n; 4 b-tiles in-wave.
__global__ __launch_bounds__(256)
void wsum_k(const short* __restrict__ Wbf, const float* __restrict__ x,
            const float* __restrict__ C, float* __restrict__ sp, int uniform) {
    const int t = threadIdx.x, lane = t & 63, w = t >> 6;
    const int col = lane & 15, g = lane >> 4;
    const int n = blockIdx.y * 4 + w;
    const int chunk = blockIdx.x;

    f32x4 acc[4];
#pragma unroll
    for (int bt = 0; bt < 4; ++bt) acc[bt] = (f32x4){0.f, 0.f, 0.f, 0.f};

    for (int jp = 0; jp < 32; ++jp) {
        const int jq = chunk * 64 + jp * 2 + (g >> 1);
        // A[m=col=d][k]: k 0..15 -> j0, 16..31 -> j1; wave reads 1KB contiguous
        bf16x8 af = *(const bf16x8*)(Wbf + ((size_t)n * J_DIM + jq) * 256 + col * 16 + (g & 1) * 8);
#pragma unroll
        for (int bt = 0; bt < 4; ++bt) {
            const int b = bt * 16 + col;
            const float4* xp = (const float4*)(x + ((size_t)b * J_DIM + jq) * 16 + (g & 1) * 8);
            float4 x0 = xp[0], x1 = xp[1];
            float cc = uniform ? 0.03125f : C[((size_t)jq * 32 + n) * 64 + b];
            short bs[8] = { f2bf(cc * x0.x), f2bf(cc * x0.y), f2bf(cc * x0.z), f2bf(cc * x0.w),
                            f2bf(cc * x1.x), f2bf(cc * x1.y), f2bf(cc * x1.z), f2bf(cc * x1.w) };
            acc[bt] = __builtin_amdgcn_mfma_f32_16x16x32_bf16(af, *(bf16x8*)bs, acc[bt], 0, 0, 0);
        }
    }
#pragma unroll
    for (int bt = 0; bt < 4; ++bt) {
        float* o = sp + (((size_t)chunk * 32 + n) * 64 + bt * 16 + col) * 16 + g * 4;
        *(float4*)o = make_float4(acc[bt][0], acc[bt][1], acc[bt][2], acc[bt][3]);
    }
}

// fold 32 chunk partials, squash, update vsum / write out. wave per (n,b).
__global__ __launch_bounds__(256)
void reduce_k(const float* __restrict__ sp, float* __restrict__ vsum,
              float* __restrict__ out, int is_last) {
    const int t = threadIdx.x, lane = t & 63, w = t >> 6;
    const int q = blockIdx.x * 4 + w;       // 0..2047
    const int n = q >> 6, b = q & 63;
    const int d4 = lane & 3, ch = lane >> 2;   // ch 0..15

    float4 a = make_float4(0.f, 0.f, 0.f, 0.f);
#pragma unroll
    for (int m = 0; m < 2; ++m) {
        float4 v = *(const float4*)(sp + (((size_t)(ch + 16 * m) * 32 + n) * 64 + b) * 16 + d4 * 4);
        a.x += v.x; a.y += v.y; a.z += v.z; a.w += v.w;
    }
#pragma unroll
    for (int mk = 4; mk <= 32; mk <<= 1) {
        a.x += __shfl_xor(a.x, mk); a.y += __shfl_xor(a.y, mk);
        a.z += __shfl_xor(a.z, mk); a.w += __shfl_xor(a.w, mk);
    }
    float tt = a.x * a.x + a.y * a.y + a.z * a.z + a.w * a.w;
    tt += __shfl_xor(tt, 1);
    tt += __shfl_xor(tt, 2);
    float s2 = tt + 1e-7f;
    float scale = sqrtf(s2) / (1.0f + s2);

    if (lane < 4) {
        float4 v = make_float4(a.x * scale, a.y * scale, a.z * scale, a.w * scale);
        float* p = (is_last ? out : vsum) + ((size_t)b * 32 + n) * 16 + d4 * 4;
        if (is_last) {
            *(float4*)p = v;
        } else {
            float4 o = *(const float4*)p;
            *(float4*)p = make_float4(o.x + v.x, o.y + v.y, o.z + v.z, o.w + v.w);
        }
    }
}

extern "C" void kernel_launch(void* const* d_in, const int* in_sizes, int n_in,
                              void* d_out, int out_size, void* d_ws, size_t ws_size,
                              hipStream_t stream) {
    const float* x = (const float*)d_in[0];   // [64,2048,16]
    const float* W = (const float*)d_in[1];   // [32,2048,16,16]
    float* out = (float*)d_out;               // [64,32,16]

    char* wsb = (char*)d_ws;
    short* Wbf  = (short*)(wsb);                         // 32 MB (+2KB slack for g>=2 tail reads)
    short* xbf  = (short*)(wsb + 33556480);              // 4 MB
    float* C    = (float*)(wsb + 37750784);              // 16 MB  [j][n][b]
    float* sp   = (float*)(wsb + 54528000);              // 4 MB   [chunk][n][b][d]
    float* vsum = (float*)(wsb + 58722304);              // 128 KB [b][n][d]

    cvt_bf16<<<8192, 256, 0, stream>>>(W, Wbf, 2097152);
    cvt_bf16<<<1024, 256, 0, stream>>>(x, xbf, 262144);
    hipMemsetAsync(vsum, 0, 64 * 32 * 16 * sizeof(float), stream);

    // pass 0: logits == 0 -> uniform c
    wsum_k<<<dim3(32, 8), 256, 0, stream>>>(Wbf, x, C, sp, 1);
    reduce_k<<<512, 256, 0, stream>>>(sp, vsum, out, 0);
    // pass 1
    logits_softmax_k<<<2048, 256, 0, stream>>>(Wbf, xbf, vsum, C);
    wsum_k<<<dim3(32, 8), 256, 0, stream>>>(Wbf, x, C, sp, 0);
    reduce_k<<<512, 256, 0, stream>>>(sp, vsum, out, 0);
    // pass 2
    logits_softmax_k<<<2048, 256, 0, stream>>>(Wbf, xbf, vsum, C);
    wsum_k<<<dim3(32, 8), 256, 0, stream>>>(Wbf, x, C, sp, 0);
    reduce_k<<<512, 256, 0, stream>>>(sp, vsum, out, 1);
}

// Round 5
// 302.320 us; speedup vs baseline: 1.1509x; 1.1509x over previous
//
#include <hip/hip_runtime.h>
#include <hip/hip_bf16.h>

// Capsule dynamic routing, round 5: round-4 structure with wsum occupancy fixed.
// x[64][2048][16] f32, W[32][2048][16][16] f32 -> v[64][32][16] f32.
//
// Identity: b_k = (sum_{i<k} v_i) . u_hat -> carry only vsum[64][32][16].
// Pass 0: c uniform (1/32) -> wsum+reduce. Passes 1,2: LS (fused
// logits+softmax -> C), wsum, reduce.
//
// wsum: wave = (chunk of 16 j, n); 4 b-tiles inside the wave (Wbf frag read
// ONCE per wave, 4 independent MFMA acc chains for ILP). grid(128,8) = 1024
// blocks = 4096 waves = 4/SIMD -- round 4's 1024-wave version was pure
// latency exposure (Occ 9.5%, VALUBusy 11%). K=32 packs 2 j per MFMA.
// sp[128][32][64][16] partials (16.8 MB); reduce folds 128 chunks + squash.
//
// MFMA layouts (m89/m91/m120-verified): C/D col=lane&15, row=(lane>>4)*4+reg;
// A[m=lane&15][k=(lane>>4)*8+t].

#define J_DIM 2048
#define NCH 128            // wsum j-chunks (16 j each)

typedef __attribute__((ext_vector_type(8))) short bf16x8;
typedef __attribute__((ext_vector_type(4))) float f32x4;

__device__ inline short f2bf(float f) {
    union { float f; unsigned u; } v; v.f = f;
    unsigned r = v.u + 0x7FFFu + ((v.u >> 16) & 1u);   // RNE
    return (short)(r >> 16);
}

__global__ __launch_bounds__(256)
void cvt_bf16(const float* __restrict__ src, short* __restrict__ dst, int n8) {
    int id = blockIdx.x * 256 + threadIdx.x;
    if (id >= n8) return;
    const float4* s = (const float4*)(src + (size_t)id * 8);
    float4 a = s[0], b = s[1];
    short t[8] = { f2bf(a.x), f2bf(a.y), f2bf(a.z), f2bf(a.w),
                   f2bf(b.x), f2bf(b.y), f2bf(b.z), f2bf(b.w) };
    *(bf16x8*)(dst + (size_t)id * 8) = *(bf16x8*)t;
}

// C[j][n][b] = softmax_n( vsum[b,n,:] . u_hat[b,n,j,:] )
// grid(2048) x 256 thr; wave = b-tile, block = one j. 8 waves/SIMD.
__global__ __launch_bounds__(256)
void logits_softmax_k(const short* __restrict__ Wbf, const short* __restrict__ xbf,
                      const float* __restrict__ vsum, float* __restrict__ C) {
    const int t = threadIdx.x, lane = t & 63, bt = t >> 6;
    const int col = lane & 15, g = lane >> 4;
    const int j = blockIdx.x;
    const int b = bt * 16 + col;

    bf16x8 xb = (bf16x8){0, 0, 0, 0, 0, 0, 0, 0};
    if (lane < 32)
        xb = *(const bf16x8*)(xbf + ((size_t)b * J_DIM + j) * 16 + (g & 1) * 8);

    float logit[32];
#pragma unroll
    for (int n = 0; n < 32; ++n) {
        // A[m=col=d][k=g*8+t]; k>=16 garbage, nulled by xb=0 on lanes 32..63
        bf16x8 af = *(const bf16x8*)(Wbf + ((size_t)n * J_DIM + j) * 256 + col * 16 + g * 8);
        f32x4 u = __builtin_amdgcn_mfma_f32_16x16x32_bf16(
            af, xb, (f32x4){0.f, 0.f, 0.f, 0.f}, 0, 0, 0);
        float4 vv = *(const float4*)(vsum + ((size_t)b * 32 + n) * 16 + g * 4);
        float lp = vv.x * u[0] + vv.y * u[1] + vv.z * u[2] + vv.w * u[3];
        lp += __shfl_xor(lp, 16);
        lp += __shfl_xor(lp, 32);          // all lanes: logit(b, n)
        logit[n] = lp;
    }

    float mx = logit[0];
#pragma unroll
    for (int n = 1; n < 32; ++n) mx = fmaxf(mx, logit[n]);
    float Z = 0.f;
#pragma unroll
    for (int n = 0; n < 32; ++n) { logit[n] = __expf(logit[n] - mx); Z += logit[n]; }
    float rz = __builtin_amdgcn_rcpf(Z);

    if (g == 0) {
        float* row = C + (size_t)j * 32 * 64 + b;
#pragma unroll
        for (int n = 0; n < 32; ++n) row[n * 64] = logit[n] * rz;
    }
}

// sp[chunk][n][b][d] = sum_{j in 16-chunk} c[b,n,j] * u_hat[b,n,j,d]
// grid(128, 8) x 256 thr; wave = (chunk, n); 4 b-tiles in-wave (4 acc chains).
__global__ __launch_bounds__(256)
void wsum_k(const short* __restrict__ Wbf, const float* __restrict__ x,
            const float* __restrict__ C, float* __restrict__ sp, int uniform) {
    const int t = threadIdx.x, lane = t & 63, w = t >> 6;
    const int col = lane & 15, g = lane >> 4;
    const int n = blockIdx.y * 4 + w;
    const int chunk = blockIdx.x;

    f32x4 acc[4];
#pragma unroll
    for (int bt = 0; bt < 4; ++bt) acc[bt] = (f32x4){0.f, 0.f, 0.f, 0.f};

#pragma unroll
    for (int jp = 0; jp < 8; ++jp) {
        const int jq = chunk * 16 + jp * 2 + (g >> 1);
        // A[m=col=d][k]: k 0..15 -> j0, 16..31 -> j1; wave reads 1KB contiguous
        bf16x8 af = *(const bf16x8*)(Wbf + ((size_t)n * J_DIM + jq) * 256 + col * 16 + (g & 1) * 8);
#pragma unroll
        for (int bt = 0; bt < 4; ++bt) {
            const int b = bt * 16 + col;
            const float4* xp = (const float4*)(x + ((size_t)b * J_DIM + jq) * 16 + (g & 1) * 8);
            float4 x0 = xp[0], x1 = xp[1];
            float cc = uniform ? 0.03125f : C[((size_t)jq * 32 + n) * 64 + b];
            short bs[8] = { f2bf(cc * x0.x), f2bf(cc * x0.y), f2bf(cc * x0.z), f2bf(cc * x0.w),
                            f2bf(cc * x1.x), f2bf(cc * x1.y), f2bf(cc * x1.z), f2bf(cc * x1.w) };
            acc[bt] = __builtin_amdgcn_mfma_f32_16x16x32_bf16(af, *(bf16x8*)bs, acc[bt], 0, 0, 0);
        }
    }
#pragma unroll
    for (int bt = 0; bt < 4; ++bt) {
        float* o = sp + (((size_t)chunk * 32 + n) * 64 + bt * 16 + col) * 16 + g * 4;
        *(float4*)o = make_float4(acc[bt][0], acc[bt][1], acc[bt][2], acc[bt][3]);
    }
}

// fold NCH chunk partials, squash, update vsum / write out. wave per (n,b).
__global__ __launch_bounds__(256)
void reduce_k(const float* __restrict__ sp, float* __restrict__ vsum,
              float* __restrict__ out, int is_last) {
    const int t = threadIdx.x, lane = t & 63, w = t >> 6;
    const int q = blockIdx.x * 4 + w;       // 0..2047
    const int n = q >> 6, b = q & 63;
    const int d4 = lane & 3, ch = lane >> 2;   // ch 0..15

    float4 a = make_float4(0.f, 0.f, 0.f, 0.f);
#pragma unroll
    for (int m = 0; m < NCH / 16; ++m) {
        float4 v = *(const float4*)(sp + (((size_t)(ch + 16 * m) * 32 + n) * 64 + b) * 16 + d4 * 4);
        a.x += v.x; a.y += v.y; a.z += v.z; a.w += v.w;
    }
#pragma unroll
    for (int mk = 4; mk <= 32; mk <<= 1) {
        a.x += __shfl_xor(a.x, mk); a.y += __shfl_xor(a.y, mk);
        a.z += __shfl_xor(a.z, mk); a.w += __shfl_xor(a.w, mk);
    }
    float tt = a.x * a.x + a.y * a.y + a.z * a.z + a.w * a.w;
    tt += __shfl_xor(tt, 1);
    tt += __shfl_xor(tt, 2);
    float s2 = tt + 1e-7f;
    float scale = sqrtf(s2) / (1.0f + s2);

    if (lane < 4) {
        float4 v = make_float4(a.x * scale, a.y * scale, a.z * scale, a.w * scale);
        float* p = (is_last ? out : vsum) + ((size_t)b * 32 + n) * 16 + d4 * 4;
        if (is_last) {
            *(float4*)p = v;
        } else {
            float4 o = *(const float4*)p;
            *(float4*)p = make_float4(o.x + v.x, o.y + v.y, o.z + v.z, o.w + v.w);
        }
    }
}

extern "C" void kernel_launch(void* const* d_in, const int* in_sizes, int n_in,
                              void* d_out, int out_size, void* d_ws, size_t ws_size,
                              hipStream_t stream) {
    const float* x = (const float*)d_in[0];   // [64,2048,16]
    const float* W = (const float*)d_in[1];   // [32,2048,16,16]
    float* out = (float*)d_out;               // [64,32,16]

    char* wsb = (char*)d_ws;
    short* Wbf  = (short*)(wsb);                         // 33.5 MB (+2KB slack)
    short* xbf  = (short*)(wsb + 33556480);              // 4.2 MB
    float* C    = (float*)(wsb + 37750784);              // 16.8 MB [j][n][b]
    float* sp   = (float*)(wsb + 54528000);              // 16.8 MB [chunk][n][b][d]
    float* vsum = (float*)(wsb + 71305216);              // 128 KB  [b][n][d]

    cvt_bf16<<<8192, 256, 0, stream>>>(W, Wbf, 2097152);
    cvt_bf16<<<1024, 256, 0, stream>>>(x, xbf, 262144);
    hipMemsetAsync(vsum, 0, 64 * 32 * 16 * sizeof(float), stream);

    // pass 0: logits == 0 -> uniform c
    wsum_k<<<dim3(NCH, 8), 256, 0, stream>>>(Wbf, x, C, sp, 1);
    reduce_k<<<512, 256, 0, stream>>>(sp, vsum, out, 0);
    // pass 1
    logits_softmax_k<<<2048, 256, 0, stream>>>(Wbf, xbf, vsum, C);
    wsum_k<<<dim3(NCH, 8), 256, 0, stream>>>(Wbf, x, C, sp, 0);
    reduce_k<<<512, 256, 0, stream>>>(sp, vsum, out, 0);
    // pass 2
    logits_softmax_k<<<2048, 256, 0, stream>>>(Wbf, xbf, vsum, C);
    wsum_k<<<dim3(NCH, 8), 256, 0, stream>>>(Wbf, x, C, sp, 0);
    reduce_k<<<512, 256, 0, stream>>>(sp, vsum, out, 1);
}

// Round 6
// 224.158 us; speedup vs baseline: 1.5522x; 1.3487x over previous
//
#include <hip/hip_runtime.h>
#include <hip/hip_bf16.h>

// Capsule dynamic routing, round 6: transposed operand layouts for contiguity.
// x[64][2048][16] f32, W[32][2048][16][16] f32 -> v[64][32][16] f32.
//
// Round-5 LS was HBM/L2-inefficient by LAYOUT: block j read 32 rows of 512B at
// 512KB stride (hbm_gbps ~1050 while streaming all of Wbf). Fix: stage
// Wbf_t[j][n][256] and xbf_t[j][b][16] so each LS block touches one contiguous
// 16KB+2KB slab and each wsum block a contiguous 256KB region. vsum kept as
// [n][b][d] internally so LS's per-n vsum read is 1KB contiguous per wave.
//
// Pipeline per pass: LS (fused logits+softmax -> C[j][n][b]), wsum (K=32 packs
// 2 j per MFMA, 4 b-tiles per wave, grid 128x8 = 4 waves/SIMD), reduce (fold
// 128 chunk partials + squash). Pass 0 skips LS (logits=0 -> c uniform 1/32).
//
// MFMA layouts (m89/m91/m120-verified): C/D col=lane&15, row=(lane>>4)*4+reg;
// A[m=lane&15][k=(lane>>4)*8+t].

#define J_DIM 2048
#define NCH 128            // wsum j-chunks (16 j each)

typedef __attribute__((ext_vector_type(8))) short bf16x8;
typedef __attribute__((ext_vector_type(4))) float f32x4;

__device__ inline short f2bf(float f) {
    union { float f; unsigned u; } v; v.f = f;
    unsigned r = v.u + 0x7FFFu + ((v.u >> 16) & 1u);   // RNE
    return (short)(r >> 16);
}
__device__ inline float bf2f(short s) {
    union { unsigned u; float f; } v; v.u = ((unsigned)(unsigned short)s) << 16;
    return v.f;
}

// W[n][j][256] f32 -> Wbf_t[j][n][256] bf16. 32-thr group per (n,j) row.
__global__ __launch_bounds__(256)
void cvt_w_t(const float* __restrict__ W, short* __restrict__ Wt) {
    const int t = threadIdx.x;
    const int p = blockIdx.x * 8 + (t >> 5);   // pair id: n = p&31 (fast), j = p>>5
    const int e = (t & 31) * 8;
    const int n = p & 31, j = p >> 5;
    const float4* s = (const float4*)(W + ((size_t)n * J_DIM + j) * 256 + e);
    float4 a = s[0], b = s[1];
    short tmp[8] = { f2bf(a.x), f2bf(a.y), f2bf(a.z), f2bf(a.w),
                     f2bf(b.x), f2bf(b.y), f2bf(b.z), f2bf(b.w) };
    *(bf16x8*)(Wt + ((size_t)j * 32 + n) * 256 + e) = *(bf16x8*)tmp;
}

// x[b][j][16] f32 -> xbf_t[j][b][16] bf16. One thread per (b,j) row.
__global__ __launch_bounds__(256)
void cvt_x_t(const float* __restrict__ x, short* __restrict__ xt) {
    const int id = blockIdx.x * 256 + threadIdx.x;   // j fast for coalesced reads
    const int j = id & (J_DIM - 1), b = id >> 11;
    const float4* s = (const float4*)(x + ((size_t)b * J_DIM + j) * 16);
    float4 q0 = s[0], q1 = s[1], q2 = s[2], q3 = s[3];
    short tmp[16] = { f2bf(q0.x), f2bf(q0.y), f2bf(q0.z), f2bf(q0.w),
                      f2bf(q1.x), f2bf(q1.y), f2bf(q1.z), f2bf(q1.w),
                      f2bf(q2.x), f2bf(q2.y), f2bf(q2.z), f2bf(q2.w),
                      f2bf(q3.x), f2bf(q3.y), f2bf(q3.z), f2bf(q3.w) };
    short* d = xt + ((size_t)j * 64 + b) * 16;
    *(bf16x8*)d = *(bf16x8*)tmp;
    *(bf16x8*)(d + 8) = *(bf16x8*)&tmp[8];
}

// C[j][n][b] = softmax_n( vsumT[n,b,:] . u_hat[b,n,j,:] )
// grid(2048) x 256 thr; wave = b-tile, block = one j (16KB contiguous W slab).
__global__ __launch_bounds__(256)
void logits_softmax_k(const short* __restrict__ Wt, const short* __restrict__ xt,
                      const float* __restrict__ vsumT, float* __restrict__ C) {
    const int t = threadIdx.x, lane = t & 63, bt = t >> 6;
    const int col = lane & 15, g = lane >> 4;
    const int j = blockIdx.x;
    const int b = bt * 16 + col;

    bf16x8 xb = (bf16x8){0, 0, 0, 0, 0, 0, 0, 0};
    if (lane < 32)
        xb = *(const bf16x8*)(xt + ((size_t)j * 64 + b) * 16 + (g & 1) * 8);

    float logit[32];
#pragma unroll
    for (int n = 0; n < 32; ++n) {
        // A[m=col=d][k=g*8+t]; k>=16 lanes read garbage (nulled by xb=0)
        bf16x8 af = *(const bf16x8*)(Wt + ((size_t)j * 32 + n) * 256 + col * 16 + g * 8);
        f32x4 u = __builtin_amdgcn_mfma_f32_16x16x32_bf16(
            af, xb, (f32x4){0.f, 0.f, 0.f, 0.f}, 0, 0, 0);
        // vsumT[n][b][d]: 16 lanes x 16B contiguous per n
        float4 vv = *(const float4*)(vsumT + ((size_t)n * 64 + b) * 16 + g * 4);
        float lp = vv.x * u[0] + vv.y * u[1] + vv.z * u[2] + vv.w * u[3];
        lp += __shfl_xor(lp, 16);
        lp += __shfl_xor(lp, 32);          // all lanes: logit(b, n)
        logit[n] = lp;
    }

    float mx = logit[0];
#pragma unroll
    for (int n = 1; n < 32; ++n) mx = fmaxf(mx, logit[n]);
    float Z = 0.f;
#pragma unroll
    for (int n = 0; n < 32; ++n) { logit[n] = __expf(logit[n] - mx); Z += logit[n]; }
    float rz = __builtin_amdgcn_rcpf(Z);

    if (g == 0) {
        float* row = C + (size_t)j * 32 * 64 + b;
#pragma unroll
        for (int n = 0; n < 32; ++n) row[n * 64] = logit[n] * rz;
    }
}

// sp[chunk][n][b][d] = sum_{j in 16-chunk} c[b,n,j] * u_hat[b,n,j,d]
// grid(128, 8) x 256 thr; wave = (chunk, n); 4 b-tiles in-wave (4 acc chains).
__global__ __launch_bounds__(256)
void wsum_k(const short* __restrict__ Wt, const short* __restrict__ xt,
            const float* __restrict__ C, float* __restrict__ sp, int uniform) {
    const int t = threadIdx.x, lane = t & 63, w = t >> 6;
    const int col = lane & 15, g = lane >> 4;
    const int n = blockIdx.y * 4 + w;
    const int chunk = blockIdx.x;

    f32x4 acc[4];
#pragma unroll
    for (int bt = 0; bt < 4; ++bt) acc[bt] = (f32x4){0.f, 0.f, 0.f, 0.f};

#pragma unroll
    for (int jp = 0; jp < 8; ++jp) {
        const int jq = chunk * 16 + jp * 2 + (g >> 1);
        // A[m=col=d][k]: k 0..15 -> j0, 16..31 -> j1; row base (jq*32+n)
        bf16x8 af = *(const bf16x8*)(Wt + ((size_t)jq * 32 + n) * 256 + col * 16 + (g & 1) * 8);
#pragma unroll
        for (int bt = 0; bt < 4; ++bt) {
            const int b = bt * 16 + col;
            bf16x8 xr = *(const bf16x8*)(xt + ((size_t)jq * 64 + b) * 16 + (g & 1) * 8);
            float cc = uniform ? 0.03125f : C[((size_t)jq * 32 + n) * 64 + b];
            short bs[8];
#pragma unroll
            for (int k = 0; k < 8; ++k) bs[k] = f2bf(cc * bf2f(xr[k]));
            acc[bt] = __builtin_amdgcn_mfma_f32_16x16x32_bf16(af, *(bf16x8*)bs, acc[bt], 0, 0, 0);
        }
    }
#pragma unroll
    for (int bt = 0; bt < 4; ++bt) {
        float* o = sp + (((size_t)chunk * 32 + n) * 64 + bt * 16 + col) * 16 + g * 4;
        *(float4*)o = make_float4(acc[bt][0], acc[bt][1], acc[bt][2], acc[bt][3]);
    }
}

// fold NCH chunk partials, squash, update vsumT / write out. wave per (n,b).
__global__ __launch_bounds__(256)
void reduce_k(const float* __restrict__ sp, float* __restrict__ vsumT,
              float* __restrict__ out, int is_last) {
    const int t = threadIdx.x, lane = t & 63, w = t >> 6;
    const int q = blockIdx.x * 4 + w;       // 0..2047
    const int n = q >> 6, b = q & 63;
    const int d4 = lane & 3, ch = lane >> 2;   // ch 0..15

    float4 a = make_float4(0.f, 0.f, 0.f, 0.f);
#pragma unroll
    for (int m = 0; m < NCH / 16; ++m) {
        float4 v = *(const float4*)(sp + (((size_t)(ch + 16 * m) * 32 + n) * 64 + b) * 16 + d4 * 4);
        a.x += v.x; a.y += v.y; a.z += v.z; a.w += v.w;
    }
#pragma unroll
    for (int mk = 4; mk <= 32; mk <<= 1) {
        a.x += __shfl_xor(a.x, mk); a.y += __shfl_xor(a.y, mk);
        a.z += __shfl_xor(a.z, mk); a.w += __shfl_xor(a.w, mk);
    }
    float tt = a.x * a.x + a.y * a.y + a.z * a.z + a.w * a.w;
    tt += __shfl_xor(tt, 1);
    tt += __shfl_xor(tt, 2);
    float s2 = tt + 1e-7f;
    float scale = sqrtf(s2) / (1.0f + s2);

    if (lane < 4) {
        float4 v = make_float4(a.x * scale, a.y * scale, a.z * scale, a.w * scale);
        if (is_last) {
            *(float4*)(out + ((size_t)b * 32 + n) * 16 + d4 * 4) = v;   // [b][n][d]
        } else {
            float* p = vsumT + ((size_t)n * 64 + b) * 16 + d4 * 4;      // [n][b][d]
            float4 o = *(const float4*)p;
            *(float4*)p = make_float4(o.x + v.x, o.y + v.y, o.z + v.z, o.w + v.w);
        }
    }
}

extern "C" void kernel_launch(void* const* d_in, const int* in_sizes, int n_in,
                              void* d_out, int out_size, void* d_ws, size_t ws_size,
                              hipStream_t stream) {
    const float* x = (const float*)d_in[0];   // [64,2048,16]
    const float* W = (const float*)d_in[1];   // [32,2048,16,16]
    float* out = (float*)d_out;               // [64,32,16]

    char* wsb = (char*)d_ws;
    short* Wt    = (short*)(wsb);                        // 32 MB + slack (Wt region 33.5 MB)
    short* xt    = (short*)(wsb + 33556480);             // 4 MB
    float* C     = (float*)(wsb + 37750784);             // 16.8 MB [j][n][b]
    float* sp    = (float*)(wsb + 54528000);             // 16.8 MB [chunk][n][b][d]
    float* vsumT = (float*)(wsb + 71305216);             // 128 KB  [n][b][d]

    cvt_w_t<<<8192, 256, 0, stream>>>(W, Wt);
    cvt_x_t<<<512, 256, 0, stream>>>(x, xt);
    hipMemsetAsync(vsumT, 0, 64 * 32 * 16 * sizeof(float), stream);

    // pass 0: logits == 0 -> uniform c
    wsum_k<<<dim3(NCH, 8), 256, 0, stream>>>(Wt, xt, C, sp, 1);
    reduce_k<<<512, 256, 0, stream>>>(sp, vsumT, out, 0);
    // pass 1
    logits_softmax_k<<<2048, 256, 0, stream>>>(Wt, xt, vsumT, C);
    wsum_k<<<dim3(NCH, 8), 256, 0, stream>>>(Wt, xt, C, sp, 0);
    reduce_k<<<512, 256, 0, stream>>>(sp, vsumT, out, 0);
    // pass 2
    logits_softmax_k<<<2048, 256, 0, stream>>>(Wt, xt, vsumT, C);
    wsum_k<<<dim3(NCH, 8), 256, 0, stream>>>(Wt, xt, C, sp, 0);
    reduce_k<<<512, 256, 0, stream>>>(sp, vsumT, out, 1);
}

// Round 7
// 207.507 us; speedup vs baseline: 1.6767x; 1.0802x over previous
//
#include <hip/hip_runtime.h>
#include <hip/hip_bf16.h>

// Capsule dynamic routing, round 7: byte-diet edition.
// x[64][2048][16] f32, W[32][2048][16][16] f32 -> v[64][32][16] f32.
//
// Pipeline (carry only vsumT[n][b][d]):
//   cvt_x, memset vsum
//   pass0: wsum0_cvt (reads f32 W ONCE, converts+writes Wt[j][n][256] bf16 as a
//          side effect, accumulates uniform-c partials) -> reduce
//   pass1,2: LS (fused logits+softmax -> C[j][n][b] bf16), wsum, reduce
//
// Byte diet vs round 6: cvt_w kernel gone (fold into pass0: -32MB Wt read,
// -1 launch), C stored bf16 (c*x is rounded to bf16 at the MFMA B-operand
// anyway), sp stored bf16 with NCH=256 (same sp bytes as round-6 f32/128 but
// 8 waves/SIMD in wsum for latency hiding).
//
// MFMA layouts (m89/m91/m120-verified): C/D col=lane&15, row=(lane>>4)*4+reg;
// A[m=lane&15][k=(lane>>4)*8+t]. K=32 packs 2 j per MFMA (k<16 -> j0, k>=16 -> j1).

#define J_DIM 2048
#define NCH 256            // wsum j-chunks (8 j each)

typedef __attribute__((ext_vector_type(8))) short bf16x8;
typedef __attribute__((ext_vector_type(4))) short bf16x4;
typedef __attribute__((ext_vector_type(4))) float f32x4;

__device__ inline short f2bf(float f) {
    union { float f; unsigned u; } v; v.f = f;
    unsigned r = v.u + 0x7FFFu + ((v.u >> 16) & 1u);   // RNE
    return (short)(r >> 16);
}
__device__ inline float bf2f(short s) {
    union { unsigned u; float f; } v; v.u = ((unsigned)(unsigned short)s) << 16;
    return v.f;
}

// x[b][j][16] f32 -> xt[j][b][16] bf16. One thread per (b,j) row.
__global__ __launch_bounds__(256)
void cvt_x_t(const float* __restrict__ x, short* __restrict__ xt) {
    const int id = blockIdx.x * 256 + threadIdx.x;   // j fast for coalesced reads
    const int j = id & (J_DIM - 1), b = id >> 11;
    const float4* s = (const float4*)(x + ((size_t)b * J_DIM + j) * 16);
    float4 q0 = s[0], q1 = s[1], q2 = s[2], q3 = s[3];
    short tmp[16] = { f2bf(q0.x), f2bf(q0.y), f2bf(q0.z), f2bf(q0.w),
                      f2bf(q1.x), f2bf(q1.y), f2bf(q1.z), f2bf(q1.w),
                      f2bf(q2.x), f2bf(q2.y), f2bf(q2.z), f2bf(q2.w),
                      f2bf(q3.x), f2bf(q3.y), f2bf(q3.z), f2bf(q3.w) };
    short* d = xt + ((size_t)j * 64 + b) * 16;
    *(bf16x8*)d = *(bf16x8*)tmp;
    *(bf16x8*)(d + 8) = *(bf16x8*)&tmp[8];
}

// Pass 0: read W f32 (each (n,j) row touched by exactly one half-wave), convert,
// write Wt[j][n][256] bf16, and accumulate uniform-c (1/32) partials into sp.
// grid(NCH, 8) x 256 thr; wave = (chunk of 8 j, n); 4 b-tiles in-wave.
__global__ __launch_bounds__(256)
void wsum0_cvt_k(const float* __restrict__ W, short* __restrict__ Wt,
                 const short* __restrict__ xt, short* __restrict__ sp) {
    const int t = threadIdx.x, lane = t & 63, w = t >> 6;
    const int col = lane & 15, g = lane >> 4;
    const int n = blockIdx.y * 4 + w;
    const int chunk = blockIdx.x;

    f32x4 acc[4];
#pragma unroll
    for (int bt = 0; bt < 4; ++bt) acc[bt] = (f32x4){0.f, 0.f, 0.f, 0.f};

#pragma unroll
    for (int jp = 0; jp < 4; ++jp) {
        const int jq = chunk * 8 + jp * 2 + (g >> 1);
        // lane's 8 f32 of W[n][jq] row; half-wave covers the full 1KB row
        const float4* wsrc = (const float4*)(W + ((size_t)n * J_DIM + jq) * 256 + col * 16 + (g & 1) * 8);
        float4 a = wsrc[0], b2 = wsrc[1];
        short tmp[8] = { f2bf(a.x), f2bf(a.y), f2bf(a.z), f2bf(a.w),
                         f2bf(b2.x), f2bf(b2.y), f2bf(b2.z), f2bf(b2.w) };
        bf16x8 af = *(bf16x8*)tmp;
        *(bf16x8*)(Wt + ((size_t)jq * 32 + n) * 256 + col * 16 + (g & 1) * 8) = af;
#pragma unroll
        for (int bt = 0; bt < 4; ++bt) {
            const int b = bt * 16 + col;
            bf16x8 xr = *(const bf16x8*)(xt + ((size_t)jq * 64 + b) * 16 + (g & 1) * 8);
            short bs[8];
#pragma unroll
            for (int k = 0; k < 8; ++k) bs[k] = f2bf(0.03125f * bf2f(xr[k]));
            acc[bt] = __builtin_amdgcn_mfma_f32_16x16x32_bf16(af, *(bf16x8*)bs, acc[bt], 0, 0, 0);
        }
    }
#pragma unroll
    for (int bt = 0; bt < 4; ++bt) {
        short o[4] = { f2bf(acc[bt][0]), f2bf(acc[bt][1]), f2bf(acc[bt][2]), f2bf(acc[bt][3]) };
        *(bf16x4*)(sp + (((size_t)chunk * 32 + n) * 64 + bt * 16 + col) * 16 + g * 4) = *(bf16x4*)o;
    }
}

// C[j][n][b] bf16 = softmax_n( vsumT[n,b,:] . u_hat[b,n,j,:] )
// grid(2048) x 256 thr; wave = b-tile, block = one j (16KB contiguous Wt slab).
__global__ __launch_bounds__(256)
void logits_softmax_k(const short* __restrict__ Wt, const short* __restrict__ xt,
                      const float* __restrict__ vsumT, short* __restrict__ C) {
    const int t = threadIdx.x, lane = t & 63, bt = t >> 6;
    const int col = lane & 15, g = lane >> 4;
    const int j = blockIdx.x;
    const int b = bt * 16 + col;

    bf16x8 xb = (bf16x8){0, 0, 0, 0, 0, 0, 0, 0};
    if (lane < 32)
        xb = *(const bf16x8*)(xt + ((size_t)j * 64 + b) * 16 + (g & 1) * 8);

    float logit[32];
#pragma unroll
    for (int n = 0; n < 32; ++n) {
        // A[m=col=d][k=g*8+t]; k>=16 lanes read garbage (nulled by xb=0)
        bf16x8 af = *(const bf16x8*)(Wt + ((size_t)j * 32 + n) * 256 + col * 16 + g * 8);
        f32x4 u = __builtin_amdgcn_mfma_f32_16x16x32_bf16(
            af, xb, (f32x4){0.f, 0.f, 0.f, 0.f}, 0, 0, 0);
        float4 vv = *(const float4*)(vsumT + ((size_t)n * 64 + b) * 16 + g * 4);
        float lp = vv.x * u[0] + vv.y * u[1] + vv.z * u[2] + vv.w * u[3];
        lp += __shfl_xor(lp, 16);
        lp += __shfl_xor(lp, 32);          // all lanes: logit(b, n)
        logit[n] = lp;
    }

    float mx = logit[0];
#pragma unroll
    for (int n = 1; n < 32; ++n) mx = fmaxf(mx, logit[n]);
    float Z = 0.f;
#pragma unroll
    for (int n = 0; n < 32; ++n) { logit[n] = __expf(logit[n] - mx); Z += logit[n]; }
    float rz = __builtin_amdgcn_rcpf(Z);

    if (g == 0) {
        short* row = C + (size_t)j * 32 * 64 + b;
#pragma unroll
        for (int n = 0; n < 32; ++n) row[n * 64] = f2bf(logit[n] * rz);
    }
}

// sp[chunk][n][b][d] bf16 = sum_{j in 8-chunk} c[b,n,j] * u_hat[b,n,j,d]
// grid(NCH, 8) x 256 thr; wave = (chunk, n); 4 b-tiles in-wave; 8 waves/SIMD.
__global__ __launch_bounds__(256)
void wsum_k(const short* __restrict__ Wt, const short* __restrict__ xt,
            const short* __restrict__ C, short* __restrict__ sp) {
    const int t = threadIdx.x, lane = t & 63, w = t >> 6;
    const int col = lane & 15, g = lane >> 4;
    const int n = blockIdx.y * 4 + w;
    const int chunk = blockIdx.x;

    f32x4 acc[4];
#pragma unroll
    for (int bt = 0; bt < 4; ++bt) acc[bt] = (f32x4){0.f, 0.f, 0.f, 0.f};

#pragma unroll
    for (int jp = 0; jp < 4; ++jp) {
        const int jq = chunk * 8 + jp * 2 + (g >> 1);
        bf16x8 af = *(const bf16x8*)(Wt + ((size_t)jq * 32 + n) * 256 + col * 16 + (g & 1) * 8);
#pragma unroll
        for (int bt = 0; bt < 4; ++bt) {
            const int b = bt * 16 + col;
            bf16x8 xr = *(const bf16x8*)(xt + ((size_t)jq * 64 + b) * 16 + (g & 1) * 8);
            float cc = bf2f(C[((size_t)jq * 32 + n) * 64 + b]);
            short bs[8];
#pragma unroll
            for (int k = 0; k < 8; ++k) bs[k] = f2bf(cc * bf2f(xr[k]));
            acc[bt] = __builtin_amdgcn_mfma_f32_16x16x32_bf16(af, *(bf16x8*)bs, acc[bt], 0, 0, 0);
        }
    }
#pragma unroll
    for (int bt = 0; bt < 4; ++bt) {
        short o[4] = { f2bf(acc[bt][0]), f2bf(acc[bt][1]), f2bf(acc[bt][2]), f2bf(acc[bt][3]) };
        *(bf16x4*)(sp + (((size_t)chunk * 32 + n) * 64 + bt * 16 + col) * 16 + g * 4) = *(bf16x4*)o;
    }
}

// fold NCH bf16 chunk partials, squash, update vsumT / write out. wave per (n,b).
__global__ __launch_bounds__(256)
void reduce_k(const short* __restrict__ sp, float* __restrict__ vsumT,
              float* __restrict__ out, int is_last) {
    const int t = threadIdx.x, lane = t & 63, w = t >> 6;
    const int q = blockIdx.x * 4 + w;       // 0..2047
    const int n = q >> 6, b = q & 63;
    const int d4 = lane & 3, ch = lane >> 2;   // ch 0..15

    float4 a = make_float4(0.f, 0.f, 0.f, 0.f);
#pragma unroll
    for (int m = 0; m < NCH / 16; ++m) {
        bf16x4 v = *(const bf16x4*)(sp + (((size_t)(ch + 16 * m) * 32 + n) * 64 + b) * 16 + d4 * 4);
        a.x += bf2f(v[0]); a.y += bf2f(v[1]); a.z += bf2f(v[2]); a.w += bf2f(v[3]);
    }
#pragma unroll
    for (int mk = 4; mk <= 32; mk <<= 1) {
        a.x += __shfl_xor(a.x, mk); a.y += __shfl_xor(a.y, mk);
        a.z += __shfl_xor(a.z, mk); a.w += __shfl_xor(a.w, mk);
    }
    float tt = a.x * a.x + a.y * a.y + a.z * a.z + a.w * a.w;
    tt += __shfl_xor(tt, 1);
    tt += __shfl_xor(tt, 2);
    float s2 = tt + 1e-7f;
    float scale = sqrtf(s2) / (1.0f + s2);

    if (lane < 4) {
        float4 v = make_float4(a.x * scale, a.y * scale, a.z * scale, a.w * scale);
        if (is_last) {
            *(float4*)(out + ((size_t)b * 32 + n) * 16 + d4 * 4) = v;   // [b][n][d]
        } else {
            float* p = vsumT + ((size_t)n * 64 + b) * 16 + d4 * 4;      // [n][b][d]
            float4 o = *(const float4*)p;
            *(float4*)p = make_float4(o.x + v.x, o.y + v.y, o.z + v.z, o.w + v.w);
        }
    }
}

extern "C" void kernel_launch(void* const* d_in, const int* in_sizes, int n_in,
                              void* d_out, int out_size, void* d_ws, size_t ws_size,
                              hipStream_t stream) {
    const float* x = (const float*)d_in[0];   // [64,2048,16]
    const float* W = (const float*)d_in[1];   // [32,2048,16,16]
    float* out = (float*)d_out;               // [64,32,16]

    char* wsb = (char*)d_ws;
    short* Wt    = (short*)(wsb);                        // 32 MB + slack
    short* xt    = (short*)(wsb + 33556480);             // 4.2 MB
    short* C     = (short*)(wsb + 37750784);             // 8.4 MB  [j][n][b] bf16
    short* sp    = (short*)(wsb + 46139392);             // 16.8 MB [chunk][n][b][d] bf16
    float* vsumT = (float*)(wsb + 62916608);             // 128 KB  [n][b][d]

    cvt_x_t<<<512, 256, 0, stream>>>(x, xt);
    hipMemsetAsync(vsumT, 0, 64 * 32 * 16 * sizeof(float), stream);

    // pass 0: logits == 0 -> uniform c; W converted+transposed in-flight
    wsum0_cvt_k<<<dim3(NCH, 8), 256, 0, stream>>>(W, Wt, xt, sp);
    reduce_k<<<512, 256, 0, stream>>>(sp, vsumT, out, 0);
    // pass 1
    logits_softmax_k<<<2048, 256, 0, stream>>>(Wt, xt, vsumT, C);
    wsum_k<<<dim3(NCH, 8), 256, 0, stream>>>(Wt, xt, C, sp);
    reduce_k<<<512, 256, 0, stream>>>(sp, vsumT, out, 0);
    // pass 2
    logits_softmax_k<<<2048, 256, 0, stream>>>(Wt, xt, vsumT, C);
    wsum_k<<<dim3(NCH, 8), 256, 0, stream>>>(Wt, xt, C, sp);
    reduce_k<<<512, 256, 0, stream>>>(sp, vsumT, out, 1);
}

// Round 8
// 200.942 us; speedup vs baseline: 1.7315x; 1.0327x over previous
//
#include <hip/hip_runtime.h>
#include <hip/hip_bf16.h>

// Capsule dynamic routing, round 8: NCH=128, memset folded into reduce (is_first).
// x[64][2048][16] f32, W[32][2048][16][16] f32 -> v[64][32][16] f32.
//
// Pipeline (carry only vsumT[n][b][d]):
//   cvt_x
//   pass0: wsum0_cvt (reads f32 W ONCE, converts+writes Wt[j][n][256] bf16,
//          accumulates uniform-c partials) -> reduce(first=1)
//   pass1,2: LS (fused logits+softmax -> C[j][n][b] bf16), wsum, reduce
//   9 dispatches total.
//
// Round-8 deltas vs 7: NCH 256->128 (sp bf16 8.4 MB, halves sp round-trip;
// round 6 proved 4 waves/SIMD suffices for wsum), reduce pass-0 STORES vsum
// (memset dispatch deleted).
//
// MFMA layouts (m89/m91/m120-verified): C/D col=lane&15, row=(lane>>4)*4+reg;
// A[m=lane&15][k=(lane>>4)*8+t]. K=32 packs 2 j per MFMA (k<16 -> j0, k>=16 -> j1).

#define J_DIM 2048
#define NCH 128            // wsum j-chunks (16 j each)

typedef __attribute__((ext_vector_type(8))) short bf16x8;
typedef __attribute__((ext_vector_type(4))) short bf16x4;
typedef __attribute__((ext_vector_type(4))) float f32x4;

__device__ inline short f2bf(float f) {
    union { float f; unsigned u; } v; v.f = f;
    unsigned r = v.u + 0x7FFFu + ((v.u >> 16) & 1u);   // RNE
    return (short)(r >> 16);
}
__device__ inline float bf2f(short s) {
    union { unsigned u; float f; } v; v.u = ((unsigned)(unsigned short)s) << 16;
    return v.f;
}

// x[b][j][16] f32 -> xt[j][b][16] bf16. One thread per (b,j) row.
__global__ __launch_bounds__(256)
void cvt_x_t(const float* __restrict__ x, short* __restrict__ xt) {
    const int id = blockIdx.x * 256 + threadIdx.x;   // j fast for coalesced reads
    const int j = id & (J_DIM - 1), b = id >> 11;
    const float4* s = (const float4*)(x + ((size_t)b * J_DIM + j) * 16);
    float4 q0 = s[0], q1 = s[1], q2 = s[2], q3 = s[3];
    short tmp[16] = { f2bf(q0.x), f2bf(q0.y), f2bf(q0.z), f2bf(q0.w),
                      f2bf(q1.x), f2bf(q1.y), f2bf(q1.z), f2bf(q1.w),
                      f2bf(q2.x), f2bf(q2.y), f2bf(q2.z), f2bf(q2.w),
                      f2bf(q3.x), f2bf(q3.y), f2bf(q3.z), f2bf(q3.w) };
    short* d = xt + ((size_t)j * 64 + b) * 16;
    *(bf16x8*)d = *(bf16x8*)tmp;
    *(bf16x8*)(d + 8) = *(bf16x8*)&tmp[8];
}

// Pass 0: read W f32 once, convert, write Wt[j][n][256] bf16, accumulate
// uniform-c (1/32) partials. grid(NCH, 8) x 256 thr; wave = (16-j chunk, n).
__global__ __launch_bounds__(256)
void wsum0_cvt_k(const float* __restrict__ W, short* __restrict__ Wt,
                 const short* __restrict__ xt, short* __restrict__ sp) {
    const int t = threadIdx.x, lane = t & 63, w = t >> 6;
    const int col = lane & 15, g = lane >> 4;
    const int n = blockIdx.y * 4 + w;
    const int chunk = blockIdx.x;

    f32x4 acc[4];
#pragma unroll
    for (int bt = 0; bt < 4; ++bt) acc[bt] = (f32x4){0.f, 0.f, 0.f, 0.f};

#pragma unroll
    for (int jp = 0; jp < 8; ++jp) {
        const int jq = chunk * 16 + jp * 2 + (g >> 1);
        // lane's 8 f32 of W[n][jq] row; half-wave covers the full 1KB row
        const float4* wsrc = (const float4*)(W + ((size_t)n * J_DIM + jq) * 256 + col * 16 + (g & 1) * 8);
        float4 a = wsrc[0], b2 = wsrc[1];
        short tmp[8] = { f2bf(a.x), f2bf(a.y), f2bf(a.z), f2bf(a.w),
                         f2bf(b2.x), f2bf(b2.y), f2bf(b2.z), f2bf(b2.w) };
        bf16x8 af = *(bf16x8*)tmp;
        *(bf16x8*)(Wt + ((size_t)jq * 32 + n) * 256 + col * 16 + (g & 1) * 8) = af;
#pragma unroll
        for (int bt = 0; bt < 4; ++bt) {
            const int b = bt * 16 + col;
            bf16x8 xr = *(const bf16x8*)(xt + ((size_t)jq * 64 + b) * 16 + (g & 1) * 8);
            short bs[8];
#pragma unroll
            for (int k = 0; k < 8; ++k) bs[k] = f2bf(0.03125f * bf2f(xr[k]));
            acc[bt] = __builtin_amdgcn_mfma_f32_16x16x32_bf16(af, *(bf16x8*)bs, acc[bt], 0, 0, 0);
        }
    }
#pragma unroll
    for (int bt = 0; bt < 4; ++bt) {
        short o[4] = { f2bf(acc[bt][0]), f2bf(acc[bt][1]), f2bf(acc[bt][2]), f2bf(acc[bt][3]) };
        *(bf16x4*)(sp + (((size_t)chunk * 32 + n) * 64 + bt * 16 + col) * 16 + g * 4) = *(bf16x4*)o;
    }
}

// C[j][n][b] bf16 = softmax_n( vsumT[n,b,:] . u_hat[b,n,j,:] )
// grid(2048) x 256 thr; wave = b-tile, block = one j (16KB contiguous Wt slab).
__global__ __launch_bounds__(256)
void logits_softmax_k(const short* __restrict__ Wt, const short* __restrict__ xt,
                      const float* __restrict__ vsumT, short* __restrict__ C) {
    const int t = threadIdx.x, lane = t & 63, bt = t >> 6;
    const int col = lane & 15, g = lane >> 4;
    const int j = blockIdx.x;
    const int b = bt * 16 + col;

    bf16x8 xb = (bf16x8){0, 0, 0, 0, 0, 0, 0, 0};
    if (lane < 32)
        xb = *(const bf16x8*)(xt + ((size_t)j * 64 + b) * 16 + (g & 1) * 8);

    float logit[32];
#pragma unroll
    for (int n = 0; n < 32; ++n) {
        // A[m=col=d][k=g*8+t]; k>=16 lanes read garbage (nulled by xb=0)
        bf16x8 af = *(const bf16x8*)(Wt + ((size_t)j * 32 + n) * 256 + col * 16 + g * 8);
        f32x4 u = __builtin_amdgcn_mfma_f32_16x16x32_bf16(
            af, xb, (f32x4){0.f, 0.f, 0.f, 0.f}, 0, 0, 0);
        float4 vv = *(const float4*)(vsumT + ((size_t)n * 64 + b) * 16 + g * 4);
        float lp = vv.x * u[0] + vv.y * u[1] + vv.z * u[2] + vv.w * u[3];
        lp += __shfl_xor(lp, 16);
        lp += __shfl_xor(lp, 32);          // all lanes: logit(b, n)
        logit[n] = lp;
    }

    float mx = logit[0];
#pragma unroll
    for (int n = 1; n < 32; ++n) mx = fmaxf(mx, logit[n]);
    float Z = 0.f;
#pragma unroll
    for (int n = 0; n < 32; ++n) { logit[n] = __expf(logit[n] - mx); Z += logit[n]; }
    float rz = __builtin_amdgcn_rcpf(Z);

    if (g == 0) {
        short* row = C + (size_t)j * 32 * 64 + b;
#pragma unroll
        for (int n = 0; n < 32; ++n) row[n * 64] = f2bf(logit[n] * rz);
    }
}

// sp[chunk][n][b][d] bf16 = sum_{j in 16-chunk} c[b,n,j] * u_hat[b,n,j,d]
// grid(NCH, 8) x 256 thr; wave = (chunk, n); 4 b-tiles in-wave; 4 waves/SIMD.
__global__ __launch_bounds__(256)
void wsum_k(const short* __restrict__ Wt, const short* __restrict__ xt,
            const short* __restrict__ C, short* __restrict__ sp) {
    const int t = threadIdx.x, lane = t & 63, w = t >> 6;
    const int col = lane & 15, g = lane >> 4;
    const int n = blockIdx.y * 4 + w;
    const int chunk = blockIdx.x;

    f32x4 acc[4];
#pragma unroll
    for (int bt = 0; bt < 4; ++bt) acc[bt] = (f32x4){0.f, 0.f, 0.f, 0.f};

#pragma unroll
    for (int jp = 0; jp < 8; ++jp) {
        const int jq = chunk * 16 + jp * 2 + (g >> 1);
        bf16x8 af = *(const bf16x8*)(Wt + ((size_t)jq * 32 + n) * 256 + col * 16 + (g & 1) * 8);
#pragma unroll
        for (int bt = 0; bt < 4; ++bt) {
            const int b = bt * 16 + col;
            bf16x8 xr = *(const bf16x8*)(xt + ((size_t)jq * 64 + b) * 16 + (g & 1) * 8);
            float cc = bf2f(C[((size_t)jq * 32 + n) * 64 + b]);
            short bs[8];
#pragma unroll
            for (int k = 0; k < 8; ++k) bs[k] = f2bf(cc * bf2f(xr[k]));
            acc[bt] = __builtin_amdgcn_mfma_f32_16x16x32_bf16(af, *(bf16x8*)bs, acc[bt], 0, 0, 0);
        }
    }
#pragma unroll
    for (int bt = 0; bt < 4; ++bt) {
        short o[4] = { f2bf(acc[bt][0]), f2bf(acc[bt][1]), f2bf(acc[bt][2]), f2bf(acc[bt][3]) };
        *(bf16x4*)(sp + (((size_t)chunk * 32 + n) * 64 + bt * 16 + col) * 16 + g * 4) = *(bf16x4*)o;
    }
}

// fold NCH bf16 chunk partials, squash, update vsumT / write out. wave per (n,b).
// is_first: STORE vsum (replaces the memset dispatch).
__global__ __launch_bounds__(256)
void reduce_k(const short* __restrict__ sp, float* __restrict__ vsumT,
              float* __restrict__ out, int is_first, int is_last) {
    const int t = threadIdx.x, lane = t & 63, w = t >> 6;
    const int q = blockIdx.x * 4 + w;       // 0..2047
    const int n = q >> 6, b = q & 63;
    const int d4 = lane & 3, ch = lane >> 2;   // ch 0..15

    float4 a = make_float4(0.f, 0.f, 0.f, 0.f);
#pragma unroll
    for (int m = 0; m < NCH / 16; ++m) {
        bf16x4 v = *(const bf16x4*)(sp + (((size_t)(ch + 16 * m) * 32 + n) * 64 + b) * 16 + d4 * 4);
        a.x += bf2f(v[0]); a.y += bf2f(v[1]); a.z += bf2f(v[2]); a.w += bf2f(v[3]);
    }
#pragma unroll
    for (int mk = 4; mk <= 32; mk <<= 1) {
        a.x += __shfl_xor(a.x, mk); a.y += __shfl_xor(a.y, mk);
        a.z += __shfl_xor(a.z, mk); a.w += __shfl_xor(a.w, mk);
    }
    float tt = a.x * a.x + a.y * a.y + a.z * a.z + a.w * a.w;
    tt += __shfl_xor(tt, 1);
    tt += __shfl_xor(tt, 2);
    float s2 = tt + 1e-7f;
    float scale = sqrtf(s2) / (1.0f + s2);

    if (lane < 4) {
        float4 v = make_float4(a.x * scale, a.y * scale, a.z * scale, a.w * scale);
        if (is_last) {
            *(float4*)(out + ((size_t)b * 32 + n) * 16 + d4 * 4) = v;   // [b][n][d]
        } else {
            float* p = vsumT + ((size_t)n * 64 + b) * 16 + d4 * 4;      // [n][b][d]
            if (is_first) {
                *(float4*)p = v;
            } else {
                float4 o = *(const float4*)p;
                *(float4*)p = make_float4(o.x + v.x, o.y + v.y, o.z + v.z, o.w + v.w);
            }
        }
    }
}

extern "C" void kernel_launch(void* const* d_in, const int* in_sizes, int n_in,
                              void* d_out, int out_size, void* d_ws, size_t ws_size,
                              hipStream_t stream) {
    const float* x = (const float*)d_in[0];   // [64,2048,16]
    const float* W = (const float*)d_in[1];   // [32,2048,16,16]
    float* out = (float*)d_out;               // [64,32,16]

    char* wsb = (char*)d_ws;
    short* Wt    = (short*)(wsb);                        // 32 MB + slack
    short* xt    = (short*)(wsb + 33556480);             // 4.2 MB
    short* C     = (short*)(wsb + 37750784);             // 8.4 MB  [j][n][b] bf16
    short* sp    = (short*)(wsb + 46139392);             // 8.4 MB  [chunk][n][b][d] bf16
    float* vsumT = (float*)(wsb + 54528000);             // 128 KB  [n][b][d]

    cvt_x_t<<<512, 256, 0, stream>>>(x, xt);

    // pass 0: logits == 0 -> uniform c; W converted+transposed in-flight
    wsum0_cvt_k<<<dim3(NCH, 8), 256, 0, stream>>>(W, Wt, xt, sp);
    reduce_k<<<512, 256, 0, stream>>>(sp, vsumT, out, 1, 0);
    // pass 1
    logits_softmax_k<<<2048, 256, 0, stream>>>(Wt, xt, vsumT, C);
    wsum_k<<<dim3(NCH, 8), 256, 0, stream>>>(Wt, xt, C, sp);
    reduce_k<<<512, 256, 0, stream>>>(sp, vsumT, out, 0, 0);
    // pass 2
    logits_softmax_k<<<2048, 256, 0, stream>>>(Wt, xt, vsumT, C);
    wsum_k<<<dim3(NCH, 8), 256, 0, stream>>>(Wt, xt, C, sp);
    reduce_k<<<512, 256, 0, stream>>>(sp, vsumT, out, 0, 1);
}